// Round 2
// baseline (121.556 us; speedup 1.0000x reference)
//
#include <hip/hip_runtime.h>

#define WID 256            // W
#define HTOT 1280          // num_img * H = 5 * 256
#define TILE_R 32          // output rows per block
#define BPB (HTOT / TILE_R) // 40 blocks per batch
#define BS 64              // batch size
#define NEG_FILL -1e9f

#define LROWS (TILE_R + 4) // 36 LDS rows (2 halo each side)
#define LSTRIDE 264        // 4 halo + 256 + 4 halo (keeps float4 stores 16B-aligned)

struct Cand { float v; int i; };

__device__ __forceinline__ bool better(float av, int ai, float bv, int bi) {
    // strict total order: larger value wins; tie -> smaller flat index (XLA top_k tie-break)
    return (av > bv) || (av == bv && ai < bi);
}

__device__ __forceinline__ void insert3(float cv, int ci,
                                        float& v0, int& i0,
                                        float& v1, int& i1,
                                        float& v2, int& i2) {
    if (better(cv, ci, v2, i2)) {
        if (better(cv, ci, v1, i1)) {
            if (better(cv, ci, v0, i0)) {
                v2 = v1; i2 = i1; v1 = v0; i1 = i0; v0 = cv; i0 = ci;
            } else {
                v2 = v1; i2 = i1; v1 = cv; i1 = ci;
            }
        } else {
            v2 = cv; i2 = ci;
        }
    }
}

__global__ __launch_bounds__(256) void peaks_phase1(const float* __restrict__ hm,
                                                    Cand* __restrict__ ws) {
    const int t  = threadIdx.x;      // 0..255 (also the column this thread owns)
    const int b  = blockIdx.y;       // batch
    const int r0 = blockIdx.x * TILE_R;
    const float NINF = -__builtin_inff();

    __shared__ float buf[LROWS * LSTRIDE];  // 36*264*4 = 38016 B

    const float* base = hm + (size_t)b * (size_t)(HTOT * WID);

    // ---- stage tile: 36 rows x 64 float4 = 2304 slots, 9 per thread, no barriers ----
    #pragma unroll
    for (int s = 0; s < 9; ++s) {
        int slot = t + s * 256;
        int row  = slot >> 6;        // 0..35
        int c4   = slot & 63;        // float4 index in row
        int gr   = r0 - 2 + row;
        float4 v;
        if (gr >= 0 && gr < HTOT) {
            v = *(const float4*)(base + (size_t)gr * WID + c4 * 4);
        } else {
            v.x = NINF; v.y = NINF; v.z = NINF; v.w = NINF;
        }
        *(float4*)&buf[row * LSTRIDE + 4 + c4 * 4] = v;
    }
    // halo columns (always outside image -> -inf): 36 rows x (4 left + 4 right)
    for (int s = t; s < LROWS * 8; s += 256) {
        int row = s >> 3;
        int j   = s & 7;
        int col = (j < 4) ? j : 256 + j;   // 0..3 left, 260..263 right
        buf[row * LSTRIDE + col] = NINF;
    }
    __syncthreads();

    // ---- separable 5x5 max, vertical shift chain, per-thread top-3 ----
    float h0 = NINF, h1 = NINF, h2 = NINF, h3 = NINF, h4 = NINF;
    float raw0 = NINF, raw1 = NINF, raw2 = NINF;
    float v0 = NINF, v1 = NINF, v2 = NINF;
    int   i0 = 0,    i1 = 0,    i2 = 0;

    const int c = t;
    #pragma unroll 4
    for (int r = 0; r < LROWS; ++r) {
        const float* rp = &buf[r * LSTRIDE + 4 + c];
        float center = rp[0];
        float m = fmaxf(fmaxf(rp[-2], rp[-1]), fmaxf(rp[1], rp[2]));
        m = fmaxf(m, center);
        h0 = h1; h1 = h2; h2 = h3; h3 = h4; h4 = m;
        raw0 = raw1; raw1 = raw2; raw2 = center;
        if (r >= 4) {
            float wmax = fmaxf(fmaxf(fmaxf(h0, h1), fmaxf(h2, h3)), h4);
            int rout = r0 + r - 4;
            float cand = (raw0 == wmax) ? raw0 : NEG_FILL;
            insert3(cand, rout * WID + c, v0, i0, v1, i1, v2, i2);
        }
    }

    // ---- block tree-reduction of per-thread top-3 (overlay LDS on buf) ----
    __syncthreads();                       // everyone done reading buf
    float* rv = buf;                       // [256*3] floats
    int*   ri = (int*)(buf + 768);         // [256*3] ints
    rv[c * 3 + 0] = v0; rv[c * 3 + 1] = v1; rv[c * 3 + 2] = v2;
    ri[c * 3 + 0] = i0; ri[c * 3 + 1] = i1; ri[c * 3 + 2] = i2;
    __syncthreads();
    for (int s = 128; s > 0; s >>= 1) {
        if (c < s) {
            insert3(rv[(c + s) * 3 + 0], ri[(c + s) * 3 + 0], v0, i0, v1, i1, v2, i2);
            insert3(rv[(c + s) * 3 + 1], ri[(c + s) * 3 + 1], v0, i0, v1, i1, v2, i2);
            insert3(rv[(c + s) * 3 + 2], ri[(c + s) * 3 + 2], v0, i0, v1, i1, v2, i2);
            rv[c * 3 + 0] = v0; rv[c * 3 + 1] = v1; rv[c * 3 + 2] = v2;
            ri[c * 3 + 0] = i0; ri[c * 3 + 1] = i1; ri[c * 3 + 2] = i2;
        }
        __syncthreads();
    }
    if (c == 0) {
        Cand* o = ws + ((size_t)b * BPB + blockIdx.x) * 3;
        o[0].v = v0; o[0].i = i0;
        o[1].v = v1; o[1].i = i1;
        o[2].v = v2; o[2].i = i2;
    }
}

__global__ __launch_bounds__(128) void peaks_phase2(const Cand* __restrict__ ws,
                                                    float* __restrict__ out) {
    const int b = blockIdx.x;
    const int t = threadIdx.x;
    const int NC = BPB * 3; // 120 candidates per batch
    const float NINF = -__builtin_inff();

    float v0 = NINF, v1 = NINF, v2 = NINF;
    int   i0 = 0,    i1 = 0,    i2 = 0;
    if (t < NC) {
        Cand e = ws[(size_t)b * NC + t];
        v0 = e.v; i0 = e.i;
    }

    __shared__ float rv[128][3];
    __shared__ int   ri[128][3];
    rv[t][0] = v0; rv[t][1] = v1; rv[t][2] = v2;
    ri[t][0] = i0; ri[t][1] = i1; ri[t][2] = i2;
    __syncthreads();
    for (int s = 64; s > 0; s >>= 1) {
        if (t < s) {
            insert3(rv[t + s][0], ri[t + s][0], v0, i0, v1, i1, v2, i2);
            insert3(rv[t + s][1], ri[t + s][1], v0, i0, v1, i1, v2, i2);
            insert3(rv[t + s][2], ri[t + s][2], v0, i0, v1, i1, v2, i2);
            rv[t][0] = v0; rv[t][1] = v1; rv[t][2] = v2;
            ri[t][0] = i0; ri[t][1] = i1; ri[t][2] = i2;
        }
        __syncthreads();
    }

    if (t == 0) {
        // positions: [bs,3,3] at offset 0 ; scores: [bs,3] at 576 ; mask: [bs,3] at 768
        float* pos = out + (size_t)b * 9;
        float* sco = out + 576 + (size_t)b * 3;
        float* msk = out + 768 + (size_t)b * 3;

        pos[0] = (float)(i0 >> 16);
        pos[1] = (float)((i0 >> 8) & 255);
        pos[2] = (float)(i0 & 255);
        sco[0] = v0;
        msk[0] = (v0 > -1e30f) ? 1.0f : 0.0f;

        pos[3] = (float)(i1 >> 16);
        pos[4] = (float)((i1 >> 8) & 255);
        pos[5] = (float)(i1 & 255);
        sco[1] = v1;
        msk[1] = (v1 > -1e30f) ? 1.0f : 0.0f;

        pos[6] = (float)(i2 >> 16);
        pos[7] = (float)((i2 >> 8) & 255);
        pos[8] = (float)(i2 & 255);
        sco[2] = v2;
        msk[2] = (v2 > -1e30f) ? 1.0f : 0.0f;
    }
}

extern "C" void kernel_launch(void* const* d_in, const int* in_sizes, int n_in,
                              void* d_out, int out_size, void* d_ws, size_t ws_size,
                              hipStream_t stream) {
    const float* hm = (const float*)d_in[0];
    float* out = (float*)d_out;
    Cand* ws = (Cand*)d_ws;  // needs 64*40*3*8 = 61440 bytes

    dim3 g1(BPB, BS);
    peaks_phase1<<<g1, 256, 0, stream>>>(hm, ws);
    peaks_phase2<<<BS, 128, 0, stream>>>(ws, out);
}

// Round 3
// 41.038 us; speedup vs baseline: 2.9620x; 2.9620x over previous
//
#include <hip/hip_runtime.h>

#define W 256
#define HTOT 1280            // num_img * H = 5 * 256
#define RR 32                // output rows per wave (stripe height)
#define SPB (HTOT / RR)      // 40 stripes per batch
#define BS 64                // batch size
#define NC (SPB * 3)         // 120 candidates per batch
#define NEG_FILL -1e9f

struct Cand { float v; int i; };

__device__ __forceinline__ bool better(float av, int ai, float bv, int bi) {
    // larger value wins; tie -> smaller flat index (XLA top_k tie-break)
    return (av > bv) || (av == bv && ai < bi);
}

__device__ __forceinline__ void merge3(float cv, int ci,
                                       float& v0, int& i0,
                                       float& v1, int& i1,
                                       float& v2, int& i2) {
    if (better(cv, ci, v2, i2)) {
        if (better(cv, ci, v1, i1)) {
            v2 = v1; i2 = i1;
            if (better(cv, ci, v0, i0)) { v1 = v0; i1 = i0; v0 = cv; i0 = ci; }
            else { v1 = cv; i1 = ci; }
        } else { v2 = cv; i2 = ci; }
    }
}

// One 64-lane wave per (batch, stripe). No LDS, no __syncthreads.
// Thread owns 4 columns; halo via shfl; 4-row software pipeline of float4 loads.
__global__ __launch_bounds__(64) void peaks_phase1(const float* __restrict__ hm,
                                                   Cand* __restrict__ ws) {
    const int lane = threadIdx.x;          // 0..63
    const int g = blockIdx.x;              // 0..2559 global wave id
    const int b = g / SPB;                 // batch (scalar)
    const int s = g - b * SPB;             // stripe
    const int r0 = s * RR;
    const float NINF = -__builtin_inff();

    const float* base = hm + (size_t)b * (size_t)(HTOT * W) + lane * 4;

    auto LOADROW = [&](int gr) -> float4 {
        float4 v;
        if ((unsigned)gr < (unsigned)HTOT) {
            v = *(const float4*)(base + (size_t)gr * W);
        } else {
            v.x = NINF; v.y = NINF; v.z = NINF; v.w = NINF;
        }
        return v;
    };

    // vertical chains: h[k][j] = horizontal 5-max of row (cur-4+k), col j
    float h[5][4];
    float raw0[4], raw1[4], raw2[4];
    #pragma unroll
    for (int k = 0; k < 5; ++k) {
        h[k][0] = NINF; h[k][1] = NINF; h[k][2] = NINF; h[k][3] = NINF;
    }
    #pragma unroll
    for (int j = 0; j < 4; ++j) { raw0[j] = NINF; raw1[j] = NINF; raw2[j] = NINF; }

    float v0 = NINF, v1 = NINF, v2 = NINF;
    int   i0 = 0x7fffffff, i1 = 0x7fffffff, i2 = 0x7fffffff;

    // software pipeline: 4 rows in flight
    float4 p0 = LOADROW(r0 - 2);
    float4 p1 = LOADROW(r0 - 1);
    float4 p2 = LOADROW(r0);
    float4 p3 = LOADROW(r0 + 1);

    #pragma unroll
    for (int r = 0; r < RR + 4; ++r) {
        float4 cur = p0;
        p0 = p1; p1 = p2; p2 = p3;
        if (r < RR) p3 = LOADROW(r0 + 2 + r);   // statically elided for r>=RR

        // halo from neighbor lanes
        float L1 = __shfl_up(cur.w, 1);    // col c0-1
        float L2 = __shfl_up(cur.z, 1);    // col c0-2
        float R1 = __shfl_down(cur.x, 1);  // col c0+4
        float R2 = __shfl_down(cur.y, 1);  // col c0+5
        if (lane == 0)  { L1 = NINF; L2 = NINF; }
        if (lane == 63) { R1 = NINF; R2 = NINF; }

        // horizontal 5-window maxes for the 4 owned columns
        float myz   = fmaxf(cur.y, cur.z);
        float mxyz  = fmaxf(cur.x, myz);
        float myzw  = fmaxf(myz, cur.w);
        float mxyzw = fmaxf(mxyz, cur.w);
        float hm0 = fmaxf(fmaxf(L2, L1), mxyz);          // cols c-2..c+2 for j=0
        float hm1 = fmaxf(L1, mxyzw);                    // j=1
        float hm2 = fmaxf(mxyzw, R1);                    // j=2
        float hm3 = fmaxf(myzw, fmaxf(R1, R2));          // j=3

        // shift vertical chains (renamed away by full unroll)
        #pragma unroll
        for (int k = 0; k < 4; ++k) {
            h[k][0] = h[k + 1][0]; h[k][1] = h[k + 1][1];
            h[k][2] = h[k + 1][2]; h[k][3] = h[k + 1][3];
        }
        h[4][0] = hm0; h[4][1] = hm1; h[4][2] = hm2; h[4][3] = hm3;
        #pragma unroll
        for (int j = 0; j < 4; ++j) { raw0[j] = raw1[j]; raw1[j] = raw2[j]; }
        raw2[0] = cur.x; raw2[1] = cur.y; raw2[2] = cur.z; raw2[3] = cur.w;

        if (r >= 4) {
            const int rout = r0 + r - 4;
            #pragma unroll
            for (int j = 0; j < 4; ++j) {
                float wmax = fmaxf(fmaxf(fmaxf(h[0][j], h[1][j]),
                                         fmaxf(h[2][j], h[3][j])), h[4][j]);
                float rv = raw0[j];
                // peak test (exact equality, same arithmetic as reference).
                // strict > keeps earliest (smallest-index) equal value ranked
                // first within this thread; non-peaks (NEG_FILL) never inserted.
                if (rv == wmax && rv > v2) {
                    int idx = rout * W + lane * 4 + j;
                    if (rv > v1) {
                        v2 = v1; i2 = i1;
                        if (rv > v0) { v1 = v0; i1 = i0; v0 = rv; i0 = idx; }
                        else         { v1 = rv; i1 = idx; }
                    } else { v2 = rv; i2 = idx; }
                }
            }
        }
    }

    // wave butterfly reduction of per-thread top-3 (full tie-break comparator)
    #pragma unroll
    for (int m = 1; m < 64; m <<= 1) {
        float a0 = __shfl_xor(v0, m), a1 = __shfl_xor(v1, m), a2 = __shfl_xor(v2, m);
        int   c0 = __shfl_xor(i0, m), c1 = __shfl_xor(i1, m), c2 = __shfl_xor(i2, m);
        merge3(a0, c0, v0, i0, v1, i1, v2, i2);
        merge3(a1, c1, v0, i0, v1, i1, v2, i2);
        merge3(a2, c2, v0, i0, v1, i1, v2, i2);
    }

    if (lane == 0) {
        Cand* o = ws + (size_t)g * 3;
        o[0].v = v0; o[0].i = i0;
        o[1].v = v1; o[1].i = i1;
        o[2].v = v2; o[2].i = i2;
    }
}

__global__ __launch_bounds__(128) void peaks_phase2(const Cand* __restrict__ ws,
                                                    float* __restrict__ out) {
    const int b = blockIdx.x;
    const int t = threadIdx.x;
    const float NINF = -__builtin_inff();

    float v0 = NINF, v1 = NINF, v2 = NINF;
    int   i0 = 0x7fffffff, i1 = 0x7fffffff, i2 = 0x7fffffff;
    if (t < NC) {
        Cand e = ws[(size_t)b * NC + t];
        v0 = e.v; i0 = e.i;
    }

    __shared__ float rv[128][3];
    __shared__ int   ri[128][3];
    rv[t][0] = v0; rv[t][1] = v1; rv[t][2] = v2;
    ri[t][0] = i0; ri[t][1] = i1; ri[t][2] = i2;
    __syncthreads();
    for (int s = 64; s > 0; s >>= 1) {
        if (t < s) {
            merge3(rv[t + s][0], ri[t + s][0], v0, i0, v1, i1, v2, i2);
            merge3(rv[t + s][1], ri[t + s][1], v0, i0, v1, i1, v2, i2);
            merge3(rv[t + s][2], ri[t + s][2], v0, i0, v1, i1, v2, i2);
            rv[t][0] = v0; rv[t][1] = v1; rv[t][2] = v2;
            ri[t][0] = i0; ri[t][1] = i1; ri[t][2] = i2;
        }
        __syncthreads();
    }

    if (t == 0) {
        // positions [64,3,3] at 0 ; scores [64,3] at 576 ; mask [64,3] at 768
        float* pos = out + (size_t)b * 9;
        float* sco = out + 576 + (size_t)b * 3;
        float* msk = out + 768 + (size_t)b * 3;

        pos[0] = (float)(i0 >> 16);
        pos[1] = (float)((i0 >> 8) & 255);
        pos[2] = (float)(i0 & 255);
        sco[0] = v0;
        msk[0] = (v0 > -1e30f) ? 1.0f : 0.0f;

        pos[3] = (float)(i1 >> 16);
        pos[4] = (float)((i1 >> 8) & 255);
        pos[5] = (float)(i1 & 255);
        sco[1] = v1;
        msk[1] = (v1 > -1e30f) ? 1.0f : 0.0f;

        pos[6] = (float)(i2 >> 16);
        pos[7] = (float)((i2 >> 8) & 255);
        pos[8] = (float)(i2 & 255);
        sco[2] = v2;
        msk[2] = (v2 > -1e30f) ? 1.0f : 0.0f;
    }
}

extern "C" void kernel_launch(void* const* d_in, const int* in_sizes, int n_in,
                              void* d_out, int out_size, void* d_ws, size_t ws_size,
                              hipStream_t stream) {
    const float* hm = (const float*)d_in[0];
    float* out = (float*)d_out;
    Cand* ws = (Cand*)d_ws;  // 64*40*3*8 = 61440 bytes

    peaks_phase1<<<BS * SPB, 64, 0, stream>>>(hm, ws);   // 2560 one-wave blocks
    peaks_phase2<<<BS, 128, 0, stream>>>(ws, out);
}